// Round 3
// baseline (506.692 us; speedup 1.0000x reference)
//
#include <hip/hip_runtime.h>

namespace {

constexpr int Hc = 32;   // heads
constexpr int Ec = 64;   // E (and D)
constexpr float EPS = 1e-6f;
constexpr float SCALE = 0.02209708691207961f;  // 2048^{-1/2}
// Row stride 68 floats: rows 16B-aligned; row*68 ≡ 4*row (mod 32) -> rows with
// distinct (row mod 8) hit distinct bank quads; conflict-free ds_read_b128.
constexpr int LDR = Ec + 4;
constexpr int LDA = Hc + 4;   // 36-float rows, same property for the 32x32 A tile
constexpr int GRID = 1792;    // 7 blocks/CU * 256 CU: exactly co-resident, no backfill tail

__device__ __forceinline__ float elu1(float x) {
    // elu(x) + 1 == (x > 0) ? x + 1 : exp(x)
    return x > 0.f ? x + 1.f : __expf(x);
}

__device__ __forceinline__ float4 elu4(float4 v) {
    v.x = elu1(v.x); v.y = elu1(v.y); v.z = elu1(v.z); v.w = elu1(v.w);
    return v;
}

__global__ __launch_bounds__(128, 4)   // cap VGPR at 128: 4 waves/SIMD possible; est. demand ~110
void linattn_kernel(const float* __restrict__ Q, const float* __restrict__ K,
                    const float* __restrict__ V, float* __restrict__ O, int npos)
{
    // Per (b,l): A[h][h'] = sum_e qf[h][e]*kf[h'][e]   (32x32, K=64, K-split by wave)
    //            A'[h][.] = A[h][.] * SCALE/(rowsum(A[h])+EPS)   (y folded into A)
    //            x[h][d]  = (A' @ V)[h][d]
    __shared__ float s_qf[Hc][LDR];
    __shared__ float s_kf[Hc][LDR];
    __shared__ float s_A [Hc][LDA];

    const int tid = threadIdx.x;
    const int p0 = (int)(((long long)blockIdx.x * npos) / GRID);
    const int p1 = (int)(((long long)(blockIdx.x + 1) * npos) / GRID);
    if (p0 >= p1) return;

    const float4* Q4 = reinterpret_cast<const float4*>(Q);
    const float4* K4 = reinterpret_cast<const float4*>(K);
    const float4* V4 = reinterpret_cast<const float4*>(V);
    float4*       O4 = reinterpret_cast<float4*>(O);

    // phase-A ids: wave wv handles e in [32*wv, 32*wv+32); 4x4 tile rows ai+8r, cols aj+8s
    const int wv = tid >> 6;
    const int ln = tid & 63;
    const int ai = ln >> 3;
    const int aj = ln & 7;
    const int eb = wv << 5;
    // phase-X ids: rows rg+8r, float4-column dg
    const int rg = tid >> 4;
    const int dg = tid & 15;

    float4 rq[4], rk[4];   // in-flight Q,K for the NEXT position (32 VGPRs resident)

    // ---- prologue: load + stage position p0; issue prefetch for p0+1 ----
    {
        const float4* qp = Q4 + (size_t)p0 * 512;
        const float4* kp = K4 + (size_t)p0 * 512;
        #pragma unroll
        for (int i = 0; i < 4; ++i) { rq[i] = qp[tid + 128 * i]; rk[i] = kp[tid + 128 * i]; }
        #pragma unroll
        for (int i = 0; i < 4; ++i) {
            const int idx = tid + 128 * i;
            const int h = idx >> 4, e4 = (idx & 15) << 2;
            *reinterpret_cast<float4*>(&s_qf[h][e4]) = elu4(rq[i]);
            *reinterpret_cast<float4*>(&s_kf[h][e4]) = elu4(rk[i]);
        }
        if (p0 + 1 < p1) {
            const float4* qn = Q4 + (size_t)(p0 + 1) * 512;
            const float4* kn = K4 + (size_t)(p0 + 1) * 512;
            #pragma unroll
            for (int i = 0; i < 4; ++i) { rq[i] = qn[tid + 128 * i]; rk[i] = kn[tid + 128 * i]; }
        }
    }
    __syncthreads();

    for (int p = p0; p < p1; ++p) {
        // ---- phase A: partial A over this wave's half of K ----
        float acc[4][4] = {};
        #pragma unroll
        for (int e = 0; e < 32; e += 4) {
            float4 a[4], b[4];
            #pragma unroll
            for (int r = 0; r < 4; ++r)
                a[r] = *reinterpret_cast<const float4*>(&s_qf[ai + 8 * r][eb + e]);
            #pragma unroll
            for (int s = 0; s < 4; ++s)
                b[s] = *reinterpret_cast<const float4*>(&s_kf[aj + 8 * s][eb + e]);
            #pragma unroll
            for (int r = 0; r < 4; ++r)
                #pragma unroll
                for (int s = 0; s < 4; ++s) {
                    acc[r][s] = fmaf(a[r].x, b[s].x, acc[r][s]);
                    acc[r][s] = fmaf(a[r].y, b[s].y, acc[r][s]);
                    acc[r][s] = fmaf(a[r].z, b[s].z, acc[r][s]);
                    acc[r][s] = fmaf(a[r].w, b[s].w, acc[r][s]);
                }
        }
        __syncthreads();   // B1: phase-A reads done; previous phase-X s_A reads done

        // B1->B2 window: wave1 parks partials; ALL threads stage pos p+1 from regs;
        // reissue prefetch for pos p+2. Staging is safe: phase-A reads ended at B1.
        if (wv == 1) {
            #pragma unroll
            for (int r = 0; r < 4; ++r)
                #pragma unroll
                for (int s = 0; s < 4; ++s)
                    s_A[ai + 8 * r][aj + 8 * s] = acc[r][s];
        }
        const bool more = (p + 1 < p1);
        if (more) {
            #pragma unroll
            for (int i = 0; i < 4; ++i) {
                const int idx = tid + 128 * i;
                const int h = idx >> 4, e4 = (idx & 15) << 2;
                *reinterpret_cast<float4*>(&s_qf[h][e4]) = elu4(rq[i]);
                *reinterpret_cast<float4*>(&s_kf[h][e4]) = elu4(rk[i]);
            }
            if (p + 2 < p1) {
                const float4* qn = Q4 + (size_t)(p + 2) * 512;
                const float4* kn = K4 + (size_t)(p + 2) * 512;
                #pragma unroll
                for (int i = 0; i < 4; ++i) { rq[i] = qn[tid + 128*i]; rk[i] = kn[tid + 128*i]; }
            }
        }
        __syncthreads();   // B2: partials + new stage visible

        if (wv == 0) {
            // combine halves, fold y*SCALE into A rows, write final A
            float fin[4][4];
            float fr[4];
            #pragma unroll
            for (int r = 0; r < 4; ++r) {
                float rs = 0.f;
                #pragma unroll
                for (int s = 0; s < 4; ++s) {
                    fin[r][s] = acc[r][s] + s_A[ai + 8 * r][aj + 8 * s];
                    rs += fin[r][s];
                }
                rs += __shfl_xor(rs, 1);   // reduce across aj lanes -> full rowsum
                rs += __shfl_xor(rs, 2);
                rs += __shfl_xor(rs, 4);
                fr[r] = SCALE / (rs + EPS);
            }
            #pragma unroll
            for (int r = 0; r < 4; ++r)
                #pragma unroll
                for (int s = 0; s < 4; ++s)
                    s_A[ai + 8 * r][aj + 8 * s] = fin[r][s] * fr[r];
        }
        __syncthreads();   // B3: final A visible

        // ---- phase X: x = A' @ V; V direct from global (wave-broadcast rows) ----
        const float4* vp = V4 + (size_t)p * 512;
        float4 x0 = {0,0,0,0}, x1 = {0,0,0,0}, x2 = {0,0,0,0}, x3 = {0,0,0,0};
        #pragma unroll
        for (int c = 0; c < 8; ++c) {
            const float4 a0 = *reinterpret_cast<const float4*>(&s_A[rg     ][c * 4]);
            const float4 a1 = *reinterpret_cast<const float4*>(&s_A[rg +  8][c * 4]);
            const float4 a2 = *reinterpret_cast<const float4*>(&s_A[rg + 16][c * 4]);
            const float4 a3 = *reinterpret_cast<const float4*>(&s_A[rg + 24][c * 4]);
            const float4 v0 = vp[(c * 4 + 0) * 16 + dg];
            const float4 v1 = vp[(c * 4 + 1) * 16 + dg];
            const float4 v2 = vp[(c * 4 + 2) * 16 + dg];
            const float4 v3 = vp[(c * 4 + 3) * 16 + dg];
            #define XROW(X, A)                                                       \
                X.x = fmaf(A.x, v0.x, X.x); X.y = fmaf(A.x, v0.y, X.y);              \
                X.z = fmaf(A.x, v0.z, X.z); X.w = fmaf(A.x, v0.w, X.w);              \
                X.x = fmaf(A.y, v1.x, X.x); X.y = fmaf(A.y, v1.y, X.y);              \
                X.z = fmaf(A.y, v1.z, X.z); X.w = fmaf(A.y, v1.w, X.w);              \
                X.x = fmaf(A.z, v2.x, X.x); X.y = fmaf(A.z, v2.y, X.y);              \
                X.z = fmaf(A.z, v2.z, X.z); X.w = fmaf(A.z, v2.w, X.w);              \
                X.x = fmaf(A.w, v3.x, X.x); X.y = fmaf(A.w, v3.y, X.y);              \
                X.z = fmaf(A.w, v3.z, X.z); X.w = fmaf(A.w, v3.w, X.w);
            XROW(x0, a0)
            XROW(x1, a1)
            XROW(x2, a2)
            XROW(x3, a3)
            #undef XROW
        }
        float4* op = O4 + (size_t)p * 512;
        op[(rg     ) * 16 + dg] = x0;   // y*SCALE already folded into A'
        op[(rg +  8) * 16 + dg] = x1;
        op[(rg + 16) * 16 + dg] = x2;
        op[(rg + 24) * 16 + dg] = x3;
    }
}

}  // namespace

extern "C" void kernel_launch(void* const* d_in, const int* in_sizes, int n_in,
                              void* d_out, int out_size, void* d_ws, size_t ws_size,
                              hipStream_t stream) {
    const float* Q = reinterpret_cast<const float*>(d_in[0]);
    const float* K = reinterpret_cast<const float*>(d_in[1]);
    const float* V = reinterpret_cast<const float*>(d_in[2]);
    float* O = reinterpret_cast<float*>(d_out);

    const int n_bl = in_sizes[0] / (Hc * Ec);   // B*L = 16384 positions
    linattn_kernel<<<GRID, 128, 0, stream>>>(Q, K, V, O, n_bl);
}